// Round 9
// baseline (190.664 us; speedup 1.0000x reference)
//
#include <hip/hip_runtime.h>
#include <hip/hip_bf16.h>
#include <math.h>

#define B_ 2
#define S_ 2048
#define D_ 1024
#define H_ 16
#define HKV_ 4
#define DH_ 64
#define NTOK (B_*S_)     // 4096
#define NQK 1280         // q(1024) + k(256) fused cols
#define NQKV 1536        // + v

typedef __attribute__((ext_vector_type(8))) short short8;
typedef __attribute__((ext_vector_type(4))) float floatx4;
typedef __attribute__((ext_vector_type(16))) float floatx16;

__device__ __forceinline__ short f2bf(float f) {
    union { __hip_bfloat16 h; short s; } u;
    u.h = __float2bfloat16(f);
    return u.s;
}
__device__ __forceinline__ float bf2f(short s) {
    union { __hip_bfloat16 h; short t; } u;
    u.t = s;
    return __bfloat162float(u.h);
}
__device__ __forceinline__ unsigned fbits(float f) {
    union { float f; unsigned u; } u; u.f = f; return u.u;
}
// pack hi16(a) | hi16(b)<<16 in ONE v_perm_b32 (RTZ bf16 truncation)
__device__ __forceinline__ unsigned packhi(float a, float b) {
    return __builtin_amdgcn_perm(fbits(b), fbits(a), 0x07060302u);
}

__device__ __forceinline__ void gload_lds16(const void* g, void* l) {
    __builtin_amdgcn_global_load_lds(
        (const __attribute__((address_space(1))) void*)g,
        (__attribute__((address_space(3))) void*)l, 16, 0, 0);
}

// ---------------- fused prep: x->bf16 convert + 4 weight transposes --------
__global__ __launch_bounds__(256) void prep_kernel(
    const float* __restrict__ x,  const float* __restrict__ Wq,
    const float* __restrict__ Wk, const float* __restrict__ Wv,
    const float* __restrict__ Wo,
    short* __restrict__ xb, short* __restrict__ wt, short* __restrict__ woT)
{
    int bid = blockIdx.x;
    if (bid < 4096) {
        int i = bid * 256 + threadIdx.x;
        float4 v = ((const float4*)x)[i];
        short4 o = { f2bf(v.x), f2bf(v.y), f2bf(v.z), f2bf(v.w) };
        ((short4*)xb)[i] = o;
        return;
    }
    bid -= 4096;
    const float* src; short* dst; int N;
    if (bid < 1024)      { src = Wq; dst = wt;                        N = 1024; }
    else if (bid < 1280) { bid -= 1024; src = Wk; dst = wt + (size_t)1024 * 1024; N = 256; }
    else if (bid < 1536) { bid -= 1280; src = Wv; dst = wt + (size_t)1280 * 1024; N = 256; }
    else                 { bid -= 1536; src = Wo; dst = woT;          N = 1024; }
    __shared__ float t[32][33];
    int tiles_n = N / 32;
    int n0 = (bid % tiles_n) * 32, k0 = (bid / tiles_n) * 32;
    int tx = threadIdx.x & 31, ty = threadIdx.x >> 5;
    #pragma unroll
    for (int i = 0; i < 4; ++i)
        t[ty + 8 * i][tx] = src[(size_t)(k0 + ty + 8 * i) * N + n0 + tx];
    __syncthreads();
    #pragma unroll
    for (int i = 0; i < 4; ++i)
        dst[(size_t)(n0 + ty + 8 * i) * 1024 + k0 + tx] = f2bf(t[tx][ty + 8 * i]);
}

// ---------------- GEMM: C[M,N] = A[M,1024] @ Bt[N,1024]^T (bf16 MFMA) -------
// 64x128 tile, BK=32, 256 thr = 4 waves as 2x2 -> wave 32 rows x 64 cols
// (acc 2x4). 3-stage LDS ring, counted vmcnt(3).
// MODE 2: K region fuses RoPE in-register in the epilogue (pair p <-> p+32 =
// acc[.][nt] <-> acc[.][nt+2], same lane); V region stores transposed with
// pi^-1 token permutation so the attention PV B-operand is pure-register.
template<int MODE>
__global__ __launch_bounds__(256, 4) void gemm_tn_kernel(
    const short* __restrict__ A, const short* __restrict__ Bt,
    short* __restrict__ Cb, float* __restrict__ Cf, short* __restrict__ Ct,
    int ldc, const int* __restrict__ poff)
{
    __shared__ short As[3][64 * 32];
    __shared__ short Bs[3][128 * 32];
    const int K = 1024;
    const int tid = threadIdx.x;
    const int bm0 = blockIdx.y * 64;
    const int bn0 = blockIdx.x * 128;
    const int lane = tid & 63, w = tid >> 6;
    const int wm = (w >> 1) * 32, wn = (w & 1) * 64;
    const int lm = lane & 15, quad = lane >> 4;

    floatx4 acc[2][4] = {};

    const int r0  = tid >> 2;         // 0..63
    const int kb0 = (tid & 3) * 16;   // byte offset within BK row

    auto stage = [&](int kt, int buf) {
        const char* gaA = (const char*)A  + ((size_t)(bm0 + r0) * K + kt) * 2 + kb0;
        const char* gaB = (const char*)Bt + ((size_t)(bn0 + r0) * K + kt) * 2 + kb0;
        gload_lds16(gaA,                      (char*)As[buf] + tid * 16);
        gload_lds16(gaB,                      (char*)Bs[buf] + tid * 16);
        gload_lds16(gaB + (size_t)64 * K * 2, (char*)Bs[buf] + 4096 + tid * 16);
    };

    stage(0, 0);
    stage(32, 1);
    for (int kt = 0; kt < K; kt += 32) {
        const int it = kt >> 5;
        const int buf = it % 3;
        if (it < (K / 32) - 1) asm volatile("s_waitcnt vmcnt(3)" ::: "memory");
        else                   asm volatile("s_waitcnt vmcnt(0)" ::: "memory");
        asm volatile("s_barrier" ::: "memory");
        if (kt + 64 < K) stage(kt + 64, (it + 2) % 3);

        short8 af[2], bfr[4];
        #pragma unroll
        for (int mt = 0; mt < 2; ++mt)
            af[mt] = *(const short8*)&As[buf][(wm + mt * 16 + lm) * 32 + quad * 8];
        #pragma unroll
        for (int nt = 0; nt < 4; ++nt)
            bfr[nt] = *(const short8*)&Bs[buf][(wn + nt * 16 + lm) * 32 + quad * 8];
        #pragma unroll
        for (int mt = 0; mt < 2; ++mt)
            #pragma unroll
            for (int nt = 0; nt < 4; ++nt)
                acc[mt][nt] = __builtin_amdgcn_mfma_f32_16x16x32_bf16(
                    af[mt], bfr[nt], acc[mt][nt], 0, 0, 0);
    }

    const int col_base = bn0 + wn;
    const int row_base = bm0 + wm;
    if (MODE == 2 && bn0 >= NQK) {  // V tiles -> transposed, pi^-1-permuted store
        #pragma unroll
        for (int mt = 0; mt < 2; ++mt)
            #pragma unroll
            for (int nt = 0; nt < 4; ++nt) {
                int vcol = col_base + nt * 16 + lm - NQK;
                int row0 = row_base + mt * 16 + quad * 4;
                // pi^-1 within 64: bit2 = old bit5, bits3..5 = old bits2..4
                int prow = (row0 & ~60) | ((row0 & 32) >> 3) | ((row0 & 0x1C) << 1);
                short4 o = { f2bf(acc[mt][nt][0]), f2bf(acc[mt][nt][1]),
                             f2bf(acc[mt][nt][2]), f2bf(acc[mt][nt][3]) };
                *(short4*)&Ct[(size_t)vcol * NTOK + prow] = o;
            }
    } else if (MODE == 1) {
        #pragma unroll
        for (int mt = 0; mt < 2; ++mt)
            #pragma unroll
            for (int nt = 0; nt < 4; ++nt)
                #pragma unroll
                for (int r = 0; r < 4; ++r) {
                    int row = row_base + mt * 16 + quad * 4 + r;
                    int col = col_base + nt * 16 + lm;
                    Cf[(size_t)row * ldc + col] = acc[mt][nt][r];
                }
    } else {
        if (MODE == 2 && bn0 >= 1024) {
            // K region: fused RoPE. p = nt*16+lm (<32) pairs with p+32 = nt+2.
            #pragma unroll
            for (int mt = 0; mt < 2; ++mt)
                #pragma unroll
                for (int r = 0; r < 4; ++r) {
                    int row = row_base + mt * 16 + quad * 4 + r;
                    float t = (float)((row & (S_ - 1)) + poff[0]);
                    #pragma unroll
                    for (int nt = 0; nt < 2; ++nt) {
                        int p = nt * 16 + lm;
                        float invf = exp2f(-0.415241012f * (float)p);
                        float ang = t * invf;
                        float sn, cs;
                        sincosf(ang, &sn, &cs);
                        float x1 = acc[mt][nt][r], x2 = acc[mt][nt + 2][r];
                        acc[mt][nt][r]     = x1 * cs - x2 * sn;
                        acc[mt][nt + 2][r] = x2 * cs + x1 * sn;
                    }
                }
        }
        #pragma unroll
        for (int mt = 0; mt < 2; ++mt)
            #pragma unroll
            for (int nt = 0; nt < 4; ++nt)
                #pragma unroll
                for (int r = 0; r < 4; ++r) {
                    int row = row_base + mt * 16 + quad * 4 + r;
                    int col = col_base + nt * 16 + lm;
                    Cb[(size_t)row * ldc + col] = f2bf(acc[mt][nt][r]);
                }
    }
}

// ---------------- attn job tables: 40 jobs per (b,h), parts <= 8 tiles -----
// C row-block; NP parts: C0-3:1, C4-7:2, C8-11:3, C12-15:4. Long jobs first.
__device__ const signed char JT_C[40]  = {15,15,15,15,14,14,14,14,13,13,13,13,
                                          12,12,12,12,11,11,11,10,10,10, 9, 9,
                                           9, 8, 8, 8, 7, 7, 6, 6, 5, 5, 4, 4,
                                           3, 2, 1, 0};
__device__ const signed char JT_k0[40] = { 0, 8,16,24, 0, 8,16,23, 0, 7,14,21,
                                           0, 7,14,20, 0, 8,16, 0, 8,15, 0, 7,
                                          14, 0, 6,12, 0, 8, 0, 7, 0, 6, 0, 5,
                                           0, 0, 0, 0};
__device__ const signed char JT_k1[40] = { 8,16,24,32, 8,16,23,30, 7,14,21,28,
                                           7,14,20,26, 8,16,24, 8,15,22, 7,14,
                                          20, 6,12,18, 8,16, 7,14, 6,12, 5,10,
                                           8, 6, 4, 2};
__device__ const signed char JT_sl[40] = {32,33,34,35,28,29,30,31,24,25,26,27,
                                          20,21,22,23,17,18,19,14,15,16,11,12,
                                          13, 8, 9,10, 6, 7, 4, 5, 2, 3, 0, 1,
                                          -1,-1,-1,-1};
// merge tables per C-4 (C = 4..15): part count and slot base within bh
__device__ const signed char MG_np[12] = {2,2,2,2,3,3,3,3,4,4,4,4};
__device__ const signed char MG_sb[12] = {0,2,4,6,8,11,14,17,20,24,28,32};
#define NSLOT 36

// ---------------- Flash attention v12: uniform fine-grained split-k --------
// 1280 jobs (40 per bh), lengths 2..8 tiles, long first -> HW backfill keeps
// ~3 blocks/CU resident throughout (fixes v10's occupancy decay 21%).
// Same per-tile structure as v10: 32x32 MFMA, in-register P via pi-permuted V,
// conflict-free swizzle f(r)=(r&7)^((r>>3)&3), 3-buf ring, counted vmcnt(4).
__global__ __launch_bounds__(256, 3) void attn_kernel12(
    const short* __restrict__ qk,  // [NTOK][1280], K cols pre-roped
    const short* __restrict__ vT,  // [256][NTOK] pi^-1-permuted tokens
    short* __restrict__ attn,      // [NTOK][1024]
    float* __restrict__ Opart,     // [1152][64][128]
    float* __restrict__ lpart,     // [1152][128]
    const int* __restrict__ poff)
{
    __shared__ short Ks[3][64 * 64];
    __shared__ short Vs[3][64 * 64];

    const int tid = threadIdx.x;
    const int lane = tid & 63, w = tid >> 6;
    const int ql = lane & 31, hi = lane >> 5;

    const int jid = blockIdx.x;
    const int bh = jid & 31;
    const int jidx = jid >> 5;
    const int C   = JT_C[jidx];
    const int kt0 = JT_k0[jidx];
    const int kt1 = JT_k1[jidx];
    const int sl  = JT_sl[jidx];
    const int pslot = (sl >= 0) ? bh * NSLOT + sl : -1;

    const int h = bh & 15, b = bh >> 4, g = h >> 2;
    const int qwb = C * 128 + w * 32;    // wave q base within batch
    const int qg  = qwb + ql;            // this lane's q row

    const short* qbase = qk + (size_t)b * S_ * NQK;
    const short* kptr  = qbase + 1024 + g * 64;
    const short* vptr  = vT + (size_t)g * 64 * NTOK + (size_t)b * S_;

    // ---- Q as B-operand frags: Qf[ds][e] = Q[d=ds*16+hi*8+e][q=qg] ----
    // RoPE + softmax scale folded in-register (pairs d <-> d+32 = ds <-> ds+2).
    short8 Qf[4];
    {
        const short* qrow = qbase + (size_t)qg * NQK + h * 64;
        short8 raw[4];
        #pragma unroll
        for (int ds = 0; ds < 4; ++ds)
            raw[ds] = *(const short8*)(qrow + ds * 16 + hi * 8);
        const float qs = 0.125f * 1.44269504f;  // 1/sqrt(64)*log2(e)
        float t = (float)(qg + poff[0]);
        #pragma unroll
        for (int ds = 0; ds < 2; ++ds)
            #pragma unroll
            for (int j = 0; j < 8; ++j) {
                int p = ds * 16 + hi * 8 + j;
                float invf = exp2f(-0.415241012f * (float)p);
                float ang = t * invf;
                float sn, cs;
                sincosf(ang, &sn, &cs);
                float x1 = bf2f(raw[ds][j]), x2 = bf2f(raw[ds + 2][j]);
                Qf[ds][j]     = f2bf(qs * (x1 * cs - x2 * sn));
                Qf[ds + 2][j] = f2bf(qs * (x2 * cs + x1 * sn));
            }
    }

    short8 ones8;
    #pragma unroll
    for (int i = 0; i < 8; ++i) ones8[i] = (short)0x3F80;  // bf16 1.0

    floatx16 O0 = {}, O1 = {}, lacc = {};

    const int sr = tid >> 3;     // 0..31
    const int cc = tid & 7;

    auto stage = [&](int kt2, int buf2) {
        const int k0s = kt2 * 64;
        #pragma unroll
        for (int i = 0; i < 2; ++i) {
            int r  = i * 32 + sr;
            int gc = cc ^ (r & 7) ^ ((r >> 3) & 3);
            gload_lds16(kptr + (size_t)(k0s + r) * NQK + gc * 8,
                        (char*)(&Ks[buf2][0]) + (i * 256 + tid) * 16);
            gload_lds16(vptr + (size_t)r * NTOK + k0s + gc * 8,
                        (char*)(&Vs[buf2][0]) + (i * 256 + tid) * 16);
        }
    };

    // swizzle key: same for rows ql and ql+32 (f(r)=f(r+32))
    const int sw2 = (ql & 7) ^ ((ql >> 3) & 3);

    auto tile = [&](int kt, int buf) {
        const int k0 = kt * 64;
        if (k0 > qwb + 31) return;               // wave fully masked
        const bool anymask = (k0 + 63 > qwb);
        floatx16 s0 = {}, s1 = {};
        __builtin_amdgcn_s_setprio(1);
        #pragma unroll
        for (int ds = 0; ds < 4; ++ds) {
            int ch = ((ds * 2 + hi) ^ sw2) * 8;
            short8 kf0 = *(const short8*)&Ks[buf][ql * 64 + ch];
            short8 kf1 = *(const short8*)&Ks[buf][(32 + ql) * 64 + ch];
            s0 = __builtin_amdgcn_mfma_f32_32x32x16_bf16(kf0, Qf[ds], s0, 0, 0, 0);
            s1 = __builtin_amdgcn_mfma_f32_32x32x16_bf16(kf1, Qf[ds], s1, 0, 0, 0);
        }
        __builtin_amdgcn_s_setprio(0);
        // exp2 + causal mask, in place
        #pragma unroll
        for (int r = 0; r < 16; ++r) {
            float v0 = exp2f(s0[r]);
            float v1 = exp2f(s1[r]);
            if (anymask) {
                int ko = k0 + (r >> 2) * 8 + hi * 4 + (r & 3);
                if (ko > qg)      v0 = 0.f;
                if (ko + 32 > qg) v1 = 0.f;
            }
            s0[r] = v0; s1[r] = v1;
        }
        // PV: B-frag for step s = pack(E0[4s..4s+3], E1[4s..4s+3]) (pi-match)
        __builtin_amdgcn_s_setprio(1);
        #pragma unroll
        for (int s = 0; s < 4; ++s) {
            uint4 u = { packhi(s0[4*s+0], s0[4*s+1]), packhi(s0[4*s+2], s0[4*s+3]),
                        packhi(s1[4*s+0], s1[4*s+1]), packhi(s1[4*s+2], s1[4*s+3]) };
            short8 bp = __builtin_bit_cast(short8, u);
            int ch = ((s * 2 + hi) ^ sw2) * 8;
            short8 vf0 = *(const short8*)&Vs[buf][ql * 64 + ch];
            short8 vf1 = *(const short8*)&Vs[buf][(32 + ql) * 64 + ch];
            O0   = __builtin_amdgcn_mfma_f32_32x32x16_bf16(vf0,   bp, O0,   0, 0, 0);
            O1   = __builtin_amdgcn_mfma_f32_32x32x16_bf16(vf1,   bp, O1,   0, 0, 0);
            lacc = __builtin_amdgcn_mfma_f32_32x32x16_bf16(ones8, bp, lacc, 0, 0, 0);
        }
        __builtin_amdgcn_s_setprio(0);
    };

    // drain Q loads so counted vmcnt below sees only stage loads
    asm volatile("s_waitcnt vmcnt(0)" ::: "memory");
    stage(kt0, 0);
    if (kt0 + 1 < kt1) stage(kt0 + 1, 1);
    for (int kt = kt0; kt < kt1; ++kt) {
        const int it = kt - kt0;
        const int buf = it % 3;
        if (kt + 1 < kt1) asm volatile("s_waitcnt vmcnt(4)" ::: "memory");
        else              asm volatile("s_waitcnt vmcnt(0)" ::: "memory");
        asm volatile("s_barrier" ::: "memory");
        if (kt + 2 < kt1) stage(kt + 2, (it + 2) % 3);
        tile(kt, buf);
    }

    if (pslot >= 0) {
        float* op = Opart + (size_t)pslot * 8192;
        const int qb = w * 32 + ql;
        #pragma unroll
        for (int r = 0; r < 16; ++r) {
            int d = (r & 3) + 8 * (r >> 2) + 4 * hi;
            op[d * 128 + qb]        = O0[r];
            op[(32 + d) * 128 + qb] = O1[r];
        }
        if (hi == 0) lpart[pslot * 128 + qb] = lacc[0];
        return;
    }
    // direct path (C<=3): lane has l(q=qg) in lacc[0]; O regs map to
    // d = dblk*32 + q4*8 + hi*4 + (r&3) -> contiguous short4 stores.
    float linv = 1.0f / lacc[0];
    short* ob = attn + (size_t)(b * S_ + qg) * D_ + h * 64;
    #pragma unroll
    for (int q4 = 0; q4 < 4; ++q4) {
        short4 a = { f2bf(O0[q4*4+0] * linv), f2bf(O0[q4*4+1] * linv),
                     f2bf(O0[q4*4+2] * linv), f2bf(O0[q4*4+3] * linv) };
        *(short4*)&ob[q4 * 8 + hi * 4] = a;
        short4 c = { f2bf(O1[q4*4+0] * linv), f2bf(O1[q4*4+1] * linv),
                     f2bf(O1[q4*4+2] * linv), f2bf(O1[q4*4+3] * linv) };
        *(short4*)&ob[32 + q4 * 8 + hi * 4] = c;
    }
}

// ---------------- merge split-k partials: 384 blocks (bh, C=4..15) ---------
__global__ __launch_bounds__(256) void attn_merge_kernel(
    const float* __restrict__ Opart, const float* __restrict__ lpart,
    short* __restrict__ attn)
{
    __shared__ float Ot[64 * 129];
    __shared__ float ls[128];
    const int bid = blockIdx.x;
    const int bh = bid & 31, ci = bid >> 5;   // ci 0..11
    const int h = bh & 15, b = bh >> 4;
    const int C = 4 + ci;
    const int np = MG_np[ci];
    const int p0 = bh * NSLOT + MG_sb[ci];
    const int tid = threadIdx.x;

    if (tid < 128) {
        float s = 0.f;
        for (int j = 0; j < np; ++j)
            s += lpart[(p0 + j) * 128 + tid];
        ls[tid] = s;
    }
    __syncthreads();

    int d = tid >> 2, q0 = (tid & 3) * 32;
    #pragma unroll
    for (int j = 0; j < 8; ++j) {
        int off = d * 128 + q0 + j * 4;
        float4 a = { 0.f, 0.f, 0.f, 0.f };
        for (int part = 0; part < np; ++part) {
            float4 v = *(const float4*)(Opart + (size_t)(p0 + part) * 8192 + off);
            a.x += v.x; a.y += v.y; a.z += v.z; a.w += v.w;
        }
        Ot[d * 129 + q0 + j * 4 + 0] = a.x / ls[q0 + j * 4 + 0];
        Ot[d * 129 + q0 + j * 4 + 1] = a.y / ls[q0 + j * 4 + 1];
        Ot[d * 129 + q0 + j * 4 + 2] = a.z / ls[q0 + j * 4 + 2];
        Ot[d * 129 + q0 + j * 4 + 3] = a.w / ls[q0 + j * 4 + 3];
    }
    __syncthreads();
    int q = tid & 127, halfd = tid >> 7;
    alignas(16) short vals[32];
    #pragma unroll
    for (int j = 0; j < 32; ++j)
        vals[j] = f2bf(Ot[(halfd * 32 + j) * 129 + q]);
    short* ob = attn + (size_t)(b * S_ + C * 128 + q) * D_ + h * 64 + halfd * 32;
    *(uint4*)&ob[0]  = *(const uint4*)&vals[0];
    *(uint4*)&ob[8]  = *(const uint4*)&vals[8];
    *(uint4*)&ob[16] = *(const uint4*)&vals[16];
    *(uint4*)&ob[24] = *(const uint4*)&vals[24];
}

extern "C" void kernel_launch(void* const* d_in, const int* in_sizes, int n_in,
                              void* d_out, int out_size, void* d_ws, size_t ws_size,
                              hipStream_t stream) {
    const float* x  = (const float*)d_in[0];
    const float* Wq = (const float*)d_in[1];
    const float* Wk = (const float*)d_in[2];
    const float* Wv = (const float*)d_in[3];
    const float* Wo = (const float*)d_in[4];
    const int* poff = (const int*)d_in[5];
    float* out = (float*)d_out;

    short* xb  = (short*)d_ws;                      // [4096][1024]
    short* wt  = xb  + (size_t)NTOK * D_;           // [1536][1024] fused Wqkv^T
    short* woT = wt  + (size_t)NQKV * D_;           // [1024][1024] Wo^T
    short* qkb = woT + (size_t)D_ * D_;             // [4096][1280]
    short* vbT = qkb + (size_t)NTOK * NQK;          // [256][4096] pi^-1-permuted
    short* ab  = vbT + (size_t)(HKV_*DH_) * NTOK;   // [4096][1024]
    float* Opart = (float*)(ab + (size_t)NTOK * D_); // [1152][64][128] fp32
    float* lpart = Opart + (size_t)1152 * 8192;      // [1152][128] fp32

    prep_kernel<<<dim3(4096 + 1024 + 256 + 256 + 1024), 256, 0, stream>>>(
        x, Wq, Wk, Wv, Wo, xb, wt, woT);
    gemm_tn_kernel<2><<<dim3(NQKV / 128, NTOK / 64), 256, 0, stream>>>(
        xb, wt, qkb, nullptr, vbT, NQK, poff);
    attn_kernel12<<<dim3(1280), 256, 0, stream>>>(qkb, vbT, ab, Opart, lpart, poff);
    attn_merge_kernel<<<dim3(384), 256, 0, stream>>>(Opart, lpart, ab);
    gemm_tn_kernel<1><<<dim3(D_ / 128, NTOK / 64), 256, 0, stream>>>(
        ab, woT, nullptr, out, nullptr, D_, poff);
}

// Round 10
// 176.167 us; speedup vs baseline: 1.0823x; 1.0823x over previous
//
#include <hip/hip_runtime.h>
#include <hip/hip_bf16.h>
#include <math.h>

#define B_ 2
#define S_ 2048
#define D_ 1024
#define H_ 16
#define HKV_ 4
#define DH_ 64
#define NTOK (B_*S_)     // 4096
#define NQK 1280         // q(1024) + k(256) fused cols
#define NQKV 1536        // + v

typedef __attribute__((ext_vector_type(8))) short short8;
typedef __attribute__((ext_vector_type(4))) float floatx4;
typedef __attribute__((ext_vector_type(16))) float floatx16;

__device__ __forceinline__ short f2bf(float f) {
    union { __hip_bfloat16 h; short s; } u;
    u.h = __float2bfloat16(f);
    return u.s;
}
__device__ __forceinline__ float bf2f(short s) {
    union { __hip_bfloat16 h; short t; } u;
    u.t = s;
    return __bfloat162float(u.h);
}
__device__ __forceinline__ unsigned fbits(float f) {
    union { float f; unsigned u; } u; u.f = f; return u.u;
}
// pack hi16(a) | hi16(b)<<16 in ONE v_perm_b32 (RTZ bf16 truncation)
__device__ __forceinline__ unsigned packhi(float a, float b) {
    return __builtin_amdgcn_perm(fbits(b), fbits(a), 0x07060302u);
}

__device__ __forceinline__ void gload_lds16(const void* g, void* l) {
    __builtin_amdgcn_global_load_lds(
        (const __attribute__((address_space(1))) void*)g,
        (__attribute__((address_space(3))) void*)l, 16, 0, 0);
}

// ---------------- fused prep: x->bf16 convert + 4 weight transposes --------
__global__ __launch_bounds__(256) void prep_kernel(
    const float* __restrict__ x,  const float* __restrict__ Wq,
    const float* __restrict__ Wk, const float* __restrict__ Wv,
    const float* __restrict__ Wo,
    short* __restrict__ xb, short* __restrict__ wt, short* __restrict__ woT)
{
    int bid = blockIdx.x;
    if (bid < 4096) {
        int i = bid * 256 + threadIdx.x;
        float4 v = ((const float4*)x)[i];
        short4 o = { f2bf(v.x), f2bf(v.y), f2bf(v.z), f2bf(v.w) };
        ((short4*)xb)[i] = o;
        return;
    }
    bid -= 4096;
    const float* src; short* dst; int N;
    if (bid < 1024)      { src = Wq; dst = wt;                        N = 1024; }
    else if (bid < 1280) { bid -= 1024; src = Wk; dst = wt + (size_t)1024 * 1024; N = 256; }
    else if (bid < 1536) { bid -= 1280; src = Wv; dst = wt + (size_t)1280 * 1024; N = 256; }
    else                 { bid -= 1536; src = Wo; dst = woT;          N = 1024; }
    __shared__ float t[32][33];
    int tiles_n = N / 32;
    int n0 = (bid % tiles_n) * 32, k0 = (bid / tiles_n) * 32;
    int tx = threadIdx.x & 31, ty = threadIdx.x >> 5;
    #pragma unroll
    for (int i = 0; i < 4; ++i)
        t[ty + 8 * i][tx] = src[(size_t)(k0 + ty + 8 * i) * N + n0 + tx];
    __syncthreads();
    #pragma unroll
    for (int i = 0; i < 4; ++i)
        dst[(size_t)(n0 + ty + 8 * i) * 1024 + k0 + tx] = f2bf(t[tx][ty + 8 * i]);
}

// ---------------- GEMM: C[M,N] = A[M,1024] @ Bt[N,1024]^T (bf16 MFMA) -------
// 64x128 tile, BK=32, 256 thr = 4 waves as 2x2 -> wave 32 rows x 64 cols
// (acc 2x4). 3-stage LDS ring, counted vmcnt(3).
// LDS bank-conflict fix (rule #21 both-sides swizzle): row r's 16B chunk c
// stored at LDS pos c ^ ((r>>1)&3) via pre-swizzled GLOBAL source (LDS dest
// stays linear for global_load_lds); ds_read XORs the same key. Read bank
// group becomes (lm%2)*16 + (quad^((lm>>1)&3))*4 -> 2 lanes/group = free
// (was 8-way, ~2.9x on the LDS pipe).
// MODE 2: K region fuses RoPE in-register in the epilogue; V region stores
// transposed with pi^-1 token permutation (attn PV B-operand pure-register).
template<int MODE>
__global__ __launch_bounds__(256, 4) void gemm_tn_kernel(
    const short* __restrict__ A, const short* __restrict__ Bt,
    short* __restrict__ Cb, float* __restrict__ Cf, short* __restrict__ Ct,
    int ldc, const int* __restrict__ poff)
{
    __shared__ short As[3][64 * 32];
    __shared__ short Bs[3][128 * 32];
    const int K = 1024;
    const int tid = threadIdx.x;
    const int bm0 = blockIdx.y * 64;
    const int bn0 = blockIdx.x * 128;
    const int lane = tid & 63, w = tid >> 6;
    const int wm = (w >> 1) * 32, wn = (w & 1) * 64;
    const int lm = lane & 15, quad = lane >> 4;

    floatx4 acc[2][4] = {};

    const int r0  = tid >> 2;                       // staged row 0..63
    const int kb0 = (((tid & 3) ^ ((r0 >> 1) & 3)) ) * 16;  // swizzled src chunk (bytes)

    auto stage = [&](int kt, int buf) {
        const char* gaA = (const char*)A  + ((size_t)(bm0 + r0) * K + kt) * 2 + kb0;
        const char* gaB = (const char*)Bt + ((size_t)(bn0 + r0) * K + kt) * 2 + kb0;
        gload_lds16(gaA,                      (char*)As[buf] + tid * 16);
        gload_lds16(gaB,                      (char*)Bs[buf] + tid * 16);
        gload_lds16(gaB + (size_t)64 * K * 2, (char*)Bs[buf] + 4096 + tid * 16);
    };

    // read swizzle key: row bases (wm+mt*16, wn+nt*16) are multiples of 16,
    // so key depends only on lm. ((64+r)>>1)&3 == (r>>1)&3 -> same for B hi.
    const int swr = (lm >> 1) & 3;

    stage(0, 0);
    stage(32, 1);
    for (int kt = 0; kt < K; kt += 32) {
        const int it = kt >> 5;
        const int buf = it % 3;
        if (it < (K / 32) - 1) asm volatile("s_waitcnt vmcnt(3)" ::: "memory");
        else                   asm volatile("s_waitcnt vmcnt(0)" ::: "memory");
        asm volatile("s_barrier" ::: "memory");
        if (kt + 64 < K) stage(kt + 64, (it + 2) % 3);

        short8 af[2], bfr[4];
        #pragma unroll
        for (int mt = 0; mt < 2; ++mt)
            af[mt] = *(const short8*)&As[buf][(wm + mt * 16 + lm) * 32 + ((quad ^ swr) * 8)];
        #pragma unroll
        for (int nt = 0; nt < 4; ++nt)
            bfr[nt] = *(const short8*)&Bs[buf][(wn + nt * 16 + lm) * 32 + ((quad ^ swr) * 8)];
        #pragma unroll
        for (int mt = 0; mt < 2; ++mt)
            #pragma unroll
            for (int nt = 0; nt < 4; ++nt)
                acc[mt][nt] = __builtin_amdgcn_mfma_f32_16x16x32_bf16(
                    af[mt], bfr[nt], acc[mt][nt], 0, 0, 0);
    }

    const int col_base = bn0 + wn;
    const int row_base = bm0 + wm;
    if (MODE == 2 && bn0 >= NQK) {  // V tiles -> transposed, pi^-1-permuted store
        #pragma unroll
        for (int mt = 0; mt < 2; ++mt)
            #pragma unroll
            for (int nt = 0; nt < 4; ++nt) {
                int vcol = col_base + nt * 16 + lm - NQK;
                int row0 = row_base + mt * 16 + quad * 4;
                // pi^-1 within 64: bit2 = old bit5, bits3..5 = old bits2..4
                int prow = (row0 & ~60) | ((row0 & 32) >> 3) | ((row0 & 0x1C) << 1);
                short4 o = { f2bf(acc[mt][nt][0]), f2bf(acc[mt][nt][1]),
                             f2bf(acc[mt][nt][2]), f2bf(acc[mt][nt][3]) };
                *(short4*)&Ct[(size_t)vcol * NTOK + prow] = o;
            }
    } else if (MODE == 1) {
        #pragma unroll
        for (int mt = 0; mt < 2; ++mt)
            #pragma unroll
            for (int nt = 0; nt < 4; ++nt)
                #pragma unroll
                for (int r = 0; r < 4; ++r) {
                    int row = row_base + mt * 16 + quad * 4 + r;
                    int col = col_base + nt * 16 + lm;
                    Cf[(size_t)row * ldc + col] = acc[mt][nt][r];
                }
    } else {
        if (MODE == 2 && bn0 >= 1024) {
            // K region: fused RoPE. p = nt*16+lm (<32) pairs with p+32 = nt+2.
            #pragma unroll
            for (int mt = 0; mt < 2; ++mt)
                #pragma unroll
                for (int r = 0; r < 4; ++r) {
                    int row = row_base + mt * 16 + quad * 4 + r;
                    float t = (float)((row & (S_ - 1)) + poff[0]);
                    #pragma unroll
                    for (int nt = 0; nt < 2; ++nt) {
                        int p = nt * 16 + lm;
                        float invf = exp2f(-0.415241012f * (float)p);
                        float ang = t * invf;
                        float sn, cs;
                        sincosf(ang, &sn, &cs);
                        float x1 = acc[mt][nt][r], x2 = acc[mt][nt + 2][r];
                        acc[mt][nt][r]     = x1 * cs - x2 * sn;
                        acc[mt][nt + 2][r] = x2 * cs + x1 * sn;
                    }
                }
        }
        #pragma unroll
        for (int mt = 0; mt < 2; ++mt)
            #pragma unroll
            for (int nt = 0; nt < 4; ++nt)
                #pragma unroll
                for (int r = 0; r < 4; ++r) {
                    int row = row_base + mt * 16 + quad * 4 + r;
                    int col = col_base + nt * 16 + lm;
                    Cb[(size_t)row * ldc + col] = f2bf(acc[mt][nt][r]);
                }
    }
}

// ---------------- Flash attention v10: 32x32 MFMA, balanced + pipelined ----
// Grid = 3 banks of 256; blocks {i, i+256, i+512} form a triple
// {split(C=15-t,h0), split(C=15-t,h1), direct(C=t)} summing to exactly 34
// tiles -> every CU gets 34 tiles (stride-256 round-robin co-location).
// LDS: 3-buffer ring, counted vmcnt(4) keeps one stage in flight across the
// barrier. Swizzle key f(r) = (r&7)^((r>>3)&3) varies within lane-mod-8
// phase groups -> conflict-free ds_read_b128.
__global__ __launch_bounds__(256, 3) void attn_kernel10(
    const short* __restrict__ qk,  // [NTOK][1280], K cols pre-roped
    const short* __restrict__ vT,  // [256][NTOK] pi^-1-permuted tokens
    short* __restrict__ attn,      // [NTOK][1024]
    float* __restrict__ Opart,     // [512][64][128]
    float* __restrict__ lpart,     // [512][128]
    const int* __restrict__ poff)
{
    __shared__ short Ks[3][64 * 64];
    __shared__ short Vs[3][64 * 64];

    const int tid = threadIdx.x;
    const int lane = tid & 63, w = tid >> 6;
    const int ql = lane & 31, hi = lane >> 5;

    const int jid = blockIdx.x;
    int bh, C, kt0, kt1, pslot;
    if (jid < 512) {               // split jobs: C = 8..15, two halves
        int i = jid & 255;
        bh = i >> 3;
        int t = i & 7;
        C = 15 - t;
        int half = jid >> 8;       // bank 0 -> half 0, bank 1 -> half 1
        kt0 = half ? (C + 1) : 0;
        kt1 = half ? (2 * C + 2) : (C + 1);
        pslot = (bh * 8 + (7 - t)) * 2 + half;
    } else {                       // direct jobs: C = 0..7
        int i = jid - 512;
        bh = i >> 3;
        C = i & 7;
        kt0 = 0; kt1 = 2 * C + 2; pslot = -1;
    }
    const int h = bh & 15, b = bh >> 4, g = h >> 2;
    const int qwb = C * 128 + w * 32;    // wave q base within batch
    const int qg  = qwb + ql;            // this lane's q row

    const short* qbase = qk + (size_t)b * S_ * NQK;
    const short* kptr  = qbase + 1024 + g * 64;
    const short* vptr  = vT + (size_t)g * 64 * NTOK + (size_t)b * S_;

    // ---- Q as B-operand frags: Qf[ds][e] = Q[d=ds*16+hi*8+e][q=qg] ----
    // RoPE + softmax scale folded in-register (pairs d <-> d+32 = ds <-> ds+2).
    short8 Qf[4];
    {
        const short* qrow = qbase + (size_t)qg * NQK + h * 64;
        short8 raw[4];
        #pragma unroll
        for (int ds = 0; ds < 4; ++ds)
            raw[ds] = *(const short8*)(qrow + ds * 16 + hi * 8);
        const float qs = 0.125f * 1.44269504f;  // 1/sqrt(64)*log2(e)
        float t = (float)(qg + poff[0]);
        #pragma unroll
        for (int ds = 0; ds < 2; ++ds)
            #pragma unroll
            for (int j = 0; j < 8; ++j) {
                int p = ds * 16 + hi * 8 + j;
                float invf = exp2f(-0.415241012f * (float)p);
                float ang = t * invf;
                float sn, cs;
                sincosf(ang, &sn, &cs);
                float x1 = bf2f(raw[ds][j]), x2 = bf2f(raw[ds + 2][j]);
                Qf[ds][j]     = f2bf(qs * (x1 * cs - x2 * sn));
                Qf[ds + 2][j] = f2bf(qs * (x2 * cs + x1 * sn));
            }
    }

    short8 ones8;
    #pragma unroll
    for (int i = 0; i < 8; ++i) ones8[i] = (short)0x3F80;  // bf16 1.0

    floatx16 O0 = {}, O1 = {}, lacc = {};

    const int sr = tid >> 3;     // 0..31
    const int cc = tid & 7;

    auto stage = [&](int kt2, int buf2) {
        const int k0s = kt2 * 64;
        #pragma unroll
        for (int i = 0; i < 2; ++i) {
            int r  = i * 32 + sr;
            int gc = cc ^ (r & 7) ^ ((r >> 3) & 3);
            gload_lds16(kptr + (size_t)(k0s + r) * NQK + gc * 8,
                        (char*)(&Ks[buf2][0]) + (i * 256 + tid) * 16);
            gload_lds16(vptr + (size_t)r * NTOK + k0s + gc * 8,
                        (char*)(&Vs[buf2][0]) + (i * 256 + tid) * 16);
        }
    };

    // swizzle key: same for rows ql and ql+32 (f(r)=f(r+32))
    const int sw2 = (ql & 7) ^ ((ql >> 3) & 3);

    auto tile = [&](int kt, int buf) {
        const int k0 = kt * 64;
        if (k0 > qwb + 31) return;               // wave fully masked
        const bool anymask = (k0 + 63 > qwb);
        floatx16 s0 = {}, s1 = {};
        __builtin_amdgcn_s_setprio(1);
        #pragma unroll
        for (int ds = 0; ds < 4; ++ds) {
            int ch = ((ds * 2 + hi) ^ sw2) * 8;
            short8 kf0 = *(const short8*)&Ks[buf][ql * 64 + ch];
            short8 kf1 = *(const short8*)&Ks[buf][(32 + ql) * 64 + ch];
            s0 = __builtin_amdgcn_mfma_f32_32x32x16_bf16(kf0, Qf[ds], s0, 0, 0, 0);
            s1 = __builtin_amdgcn_mfma_f32_32x32x16_bf16(kf1, Qf[ds], s1, 0, 0, 0);
        }
        __builtin_amdgcn_s_setprio(0);
        // exp2 + causal mask, in place
        #pragma unroll
        for (int r = 0; r < 16; ++r) {
            float v0 = exp2f(s0[r]);
            float v1 = exp2f(s1[r]);
            if (anymask) {
                int ko = k0 + (r >> 2) * 8 + hi * 4 + (r & 3);
                if (ko > qg)      v0 = 0.f;
                if (ko + 32 > qg) v1 = 0.f;
            }
            s0[r] = v0; s1[r] = v1;
        }
        // PV: B-frag for step s = pack(E0[4s..4s+3], E1[4s..4s+3]) (pi-match)
        __builtin_amdgcn_s_setprio(1);
        #pragma unroll
        for (int s = 0; s < 4; ++s) {
            uint4 u = { packhi(s0[4*s+0], s0[4*s+1]), packhi(s0[4*s+2], s0[4*s+3]),
                        packhi(s1[4*s+0], s1[4*s+1]), packhi(s1[4*s+2], s1[4*s+3]) };
            short8 bp = __builtin_bit_cast(short8, u);
            int ch = ((s * 2 + hi) ^ sw2) * 8;
            short8 vf0 = *(const short8*)&Vs[buf][ql * 64 + ch];
            short8 vf1 = *(const short8*)&Vs[buf][(32 + ql) * 64 + ch];
            O0   = __builtin_amdgcn_mfma_f32_32x32x16_bf16(vf0,   bp, O0,   0, 0, 0);
            O1   = __builtin_amdgcn_mfma_f32_32x32x16_bf16(vf1,   bp, O1,   0, 0, 0);
            lacc = __builtin_amdgcn_mfma_f32_32x32x16_bf16(ones8, bp, lacc, 0, 0, 0);
        }
        __builtin_amdgcn_s_setprio(0);
    };

    // drain Q loads so counted vmcnt below sees only stage loads
    asm volatile("s_waitcnt vmcnt(0)" ::: "memory");
    stage(kt0, 0);
    if (kt0 + 1 < kt1) stage(kt0 + 1, 1);
    for (int kt = kt0; kt < kt1; ++kt) {
        const int it = kt - kt0;
        const int buf = it % 3;
        if (kt + 1 < kt1) asm volatile("s_waitcnt vmcnt(4)" ::: "memory");
        else              asm volatile("s_waitcnt vmcnt(0)" ::: "memory");
        asm volatile("s_barrier" ::: "memory");
        if (kt + 2 < kt1) stage(kt + 2, (it + 2) % 3);
        tile(kt, buf);
    }

    if (pslot >= 0) {
        float* op = Opart + (size_t)pslot * 8192;
        const int qb = w * 32 + ql;
        #pragma unroll
        for (int r = 0; r < 16; ++r) {
            int d = (r & 3) + 8 * (r >> 2) + 4 * hi;
            op[d * 128 + qb]        = O0[r];
            op[(32 + d) * 128 + qb] = O1[r];
        }
        if (hi == 0) lpart[pslot * 128 + qb] = lacc[0];
        return;
    }
    // direct path: every lane has l(q=qg) in lacc[0]; O regs map to
    // d = dblk*32 + q4*8 + hi*4 + (r&3) -> contiguous short4 stores.
    float linv = 1.0f / lacc[0];
    short* ob = attn + (size_t)(b * S_ + qg) * D_ + h * 64;
    #pragma unroll
    for (int q4 = 0; q4 < 4; ++q4) {
        short4 a = { f2bf(O0[q4*4+0] * linv), f2bf(O0[q4*4+1] * linv),
                     f2bf(O0[q4*4+2] * linv), f2bf(O0[q4*4+3] * linv) };
        *(short4*)&ob[q4 * 8 + hi * 4] = a;
        short4 c = { f2bf(O1[q4*4+0] * linv), f2bf(O1[q4*4+1] * linv),
                     f2bf(O1[q4*4+2] * linv), f2bf(O1[q4*4+3] * linv) };
        *(short4*)&ob[32 + q4 * 8 + hi * 4] = c;
    }
}

// ---------------- merge split-k partials: 256 blocks (bh, Cm) --------------
__global__ __launch_bounds__(256) void attn_merge_kernel(
    const float* __restrict__ Opart, const float* __restrict__ lpart,
    short* __restrict__ attn)
{
    __shared__ float Ot[64 * 129];
    __shared__ float ls[128];
    const int bid = blockIdx.x;
    const int bh = bid & 31, Cm = bid >> 5;   // Cm 0..7
    const int h = bh & 15, b = bh >> 4;
    const int C = 8 + Cm;
    const int p0 = (bh * 8 + Cm) * 2;
    const int tid = threadIdx.x;

    if (tid < 128)
        ls[tid] = lpart[p0 * 128 + tid] + lpart[(p0 + 1) * 128 + tid];
    __syncthreads();

    const float* o0 = Opart + (size_t)p0 * 8192;
    const float* o1 = o0 + 8192;
    int d = tid >> 2, q0 = (tid & 3) * 32;
    #pragma unroll
    for (int j = 0; j < 8; ++j) {
        int off = d * 128 + q0 + j * 4;
        float4 a  = *(const float4*)(o0 + off);
        float4 bv = *(const float4*)(o1 + off);
        Ot[d * 129 + q0 + j * 4 + 0] = (a.x + bv.x) / ls[q0 + j * 4 + 0];
        Ot[d * 129 + q0 + j * 4 + 1] = (a.y + bv.y) / ls[q0 + j * 4 + 1];
        Ot[d * 129 + q0 + j * 4 + 2] = (a.z + bv.z) / ls[q0 + j * 4 + 2];
        Ot[d * 129 + q0 + j * 4 + 3] = (a.w + bv.w) / ls[q0 + j * 4 + 3];
    }
    __syncthreads();
    int q = tid & 127, halfd = tid >> 7;
    alignas(16) short vals[32];
    #pragma unroll
    for (int j = 0; j < 32; ++j)
        vals[j] = f2bf(Ot[(halfd * 32 + j) * 129 + q]);
    short* ob = attn + (size_t)(b * S_ + C * 128 + q) * D_ + h * 64 + halfd * 32;
    *(uint4*)&ob[0]  = *(const uint4*)&vals[0];
    *(uint4*)&ob[8]  = *(const uint4*)&vals[8];
    *(uint4*)&ob[16] = *(const uint4*)&vals[16];
    *(uint4*)&ob[24] = *(const uint4*)&vals[24];
}

extern "C" void kernel_launch(void* const* d_in, const int* in_sizes, int n_in,
                              void* d_out, int out_size, void* d_ws, size_t ws_size,
                              hipStream_t stream) {
    const float* x  = (const float*)d_in[0];
    const float* Wq = (const float*)d_in[1];
    const float* Wk = (const float*)d_in[2];
    const float* Wv = (const float*)d_in[3];
    const float* Wo = (const float*)d_in[4];
    const int* poff = (const int*)d_in[5];
    float* out = (float*)d_out;

    short* xb  = (short*)d_ws;                      // [4096][1024]
    short* wt  = xb  + (size_t)NTOK * D_;           // [1536][1024] fused Wqkv^T
    short* woT = wt  + (size_t)NQKV * D_;           // [1024][1024] Wo^T
    short* qkb = woT + (size_t)D_ * D_;             // [4096][1280]
    short* vbT = qkb + (size_t)NTOK * NQK;          // [256][4096] pi^-1-permuted
    short* ab  = vbT + (size_t)(HKV_*DH_) * NTOK;   // [4096][1024]
    float* Opart = (float*)(ab + (size_t)NTOK * D_); // [512][64][128] fp32
    float* lpart = Opart + (size_t)512 * 8192;       // [512][128] fp32

    prep_kernel<<<dim3(4096 + 1024 + 256 + 256 + 1024), 256, 0, stream>>>(
        x, Wq, Wk, Wv, Wo, xb, wt, woT);
    gemm_tn_kernel<2><<<dim3(NQKV / 128, NTOK / 64), 256, 0, stream>>>(
        xb, wt, qkb, nullptr, vbT, NQK, poff);
    attn_kernel10<<<dim3(768), 256, 0, stream>>>(qkb, vbT, ab, Opart, lpart, poff);
    attn_merge_kernel<<<dim3(256), 256, 0, stream>>>(Opart, lpart, ab);
    gemm_tn_kernel<1><<<dim3(D_ / 128, NTOK / 64), 256, 0, stream>>>(
        ab, woT, nullptr, out, nullptr, D_, poff);
}